// Round 12
// baseline (266.299 us; speedup 1.0000x reference)
//
#include <hip/hip_runtime.h>
#include <cmath>
#include <cstdint>

#define NB 32
#define NP 24564
#define NC 81
#define NEG_POS 3

static constexpr size_t MINED_ELEMS = (size_t)NB * NP;             // 786,048
static constexpr size_t MINED_BYTES = MINED_ELEMS * sizeof(float); // 3,144,192
static constexpr uint32_t CONF_BYTES = (uint32_t)(MINED_ELEMS * NC * 4); // 254,679,552
static constexpr uint32_t CONF_F4 = CONF_BYTES / 16;               // 15,917,472

#define TILE_ROWS 64
#define TILE_BYTES (TILE_ROWS * NC * 4)          // 20,736
#define NTILES ((int)(MINED_ELEMS / TILE_ROWS))  // 12,282 exact
#define TILES_PER_BLOCK 6
#define MAIN_BLOCKS (NTILES / TILES_PER_BLOCK)   // 2,047 exact
#define LDS_FLOATS 6144

#define PROBE_BLOCKS 4096

// ws layout:
//   [0, MINED_BYTES)                    float mined[NB*NP]   (probe sums land here first)
//   [MINED_BYTES, +24)                  double acc[3]
//   [MINED_BYTES+24, +24+4*NB)          int   num_pos[NB]

__device__ __forceinline__ float wave_reduce_sum(float v) {
#pragma unroll
  for (int off = 32; off > 0; off >>= 1) v += __shfl_down(v, off, 64);
  return v;
}

__device__ __forceinline__ float smooth_l1_4(float4 a, float4 t) {
  float acc = 0.f, d, ax;
  d = a.x - t.x; ax = fabsf(d); acc += (ax < 1.f) ? 0.5f * d * d : ax - 0.5f;
  d = a.y - t.y; ax = fabsf(d); acc += (ax < 1.f) ? 0.5f * d * d : ax - 0.5f;
  d = a.z - t.z; ax = fabsf(d); acc += (ax < 1.f) ? 0.5f * d * d : ax - 0.5f;
  d = a.w - t.w; ax = fabsf(d); acc += (ax < 1.f) ? 0.5f * d * d : ax - 0.5f;
  return acc;
}

// ---------- diagnostic probes (results overwritten by mb_main) ----------
__global__ __launch_bounds__(256) void probe_stream(
    const float4* __restrict__ src, float* __restrict__ out) {
  const int tid = (int)threadIdx.x;
  float s = 0.f;
  const uint32_t stride = (uint32_t)gridDim.x * 256u;
  for (uint32_t q = (uint32_t)blockIdx.x * 256u + (uint32_t)tid; q < CONF_F4; q += stride) {
    const float4 v = src[q];
    s += (v.x + v.y) + (v.z + v.w);
  }
  __shared__ float red[4];
  float w = wave_reduce_sum(s);
  if ((tid & 63) == 0) red[tid >> 6] = w;
  __syncthreads();
  if (tid == 0) out[blockIdx.x] = red[0] + red[1] + red[2] + red[3];
}

__global__ __launch_bounds__(256) void probe_exp(
    const float4* __restrict__ src, float* __restrict__ out) {
  const int tid = (int)threadIdx.x;
  float s = 0.f;
  const uint32_t stride = (uint32_t)gridDim.x * 256u;
  for (uint32_t q = (uint32_t)blockIdx.x * 256u + (uint32_t)tid; q < CONF_F4; q += stride) {
    const float4 v = src[q];
    s += (__expf(v.x) + __expf(v.y)) + (__expf(v.z) + __expf(v.w));
  }
  __shared__ float red[4];
  float w = wave_reduce_sum(s);
  if ((tid & 63) == 0) red[tid >> 6] = w;
  __syncthreads();
  if (tid == 0) out[blockIdx.x] = red[0] + red[1] + red[2] + red[3];
}

// ---------- real pipeline (R11, unchanged) ----------
__global__ void mb_init(double* __restrict__ acc, int* __restrict__ num_pos) {
  int t = threadIdx.x;
  if (t < 3) acc[t] = 0.0;
  if (t < NB) num_pos[t] = 0;
}

__device__ __forceinline__ void stage_tile(const char* __restrict__ conf_base,
                                           uint32_t tile, float* buf,
                                           int wid, int lane) {
  const uint32_t SAFE = CONF_BYTES - 16;
  uint32_t off0 = tile * (uint32_t)TILE_BYTES + (uint32_t)(wid * 6144 + lane * 16);
#pragma unroll
  for (int i = 0; i < 6; ++i) {
    uint32_t off = off0 + (uint32_t)(i * 1024);
    off = (off <= SAFE) ? off : SAFE;
    const void* g = conf_base + off;
    float* l = buf + wid * 1536 + i * 256;
    __builtin_amdgcn_global_load_lds(
        (const __attribute__((address_space(1))) void*)g,
        (__attribute__((address_space(3))) void*)l, 16, 0, 0);
  }
}

__device__ __forceinline__ void compute_tile(
    const float* __restrict__ L, int tile, int tgt, int row, int part,
    const float* __restrict__ loc_data, const float* __restrict__ loc_targets,
    float* __restrict__ mined, int* __restrict__ num_pos,
    float& loc_v, float& ce_pos) {
  const float* rp = L + row * NC + part * 20;
  float s = 0.f;
#pragma unroll
  for (int j = 0; j < 20; ++j) s += __expf(rp[j]);
  if (part == 3) s += __expf(L[row * NC + 80]);
  s += __shfl_xor(s, 1, 64);
  s += __shfl_xor(s, 2, 64);
  if (part == 0) {
    const float tv = L[row * NC + tgt];
    const float ce = __logf(s) - tv;
    const size_t flat = (size_t)tile * TILE_ROWS + row;
    const int is_pos = tgt > 0;
    mined[flat] = is_pos ? 0.f : ce;
    if (is_pos) {
      ce_pos += ce;
      loc_v += smooth_l1_4(*reinterpret_cast<const float4*>(loc_data + flat * 4),
                           *reinterpret_cast<const float4*>(loc_targets + flat * 4));
      atomicAdd(&num_pos[(int)(flat / NP)], 1);
    }
  }
}

#define DRAIN_BARRIER()                                \
  do {                                                 \
    asm volatile("s_waitcnt vmcnt(0)" ::: "memory");   \
    __builtin_amdgcn_s_barrier();                      \
  } while (0)

__global__ __launch_bounds__(256) void mb_main(
    const float* __restrict__ loc_data, const float* __restrict__ conf_data,
    const float* __restrict__ loc_targets, const int* __restrict__ conf_targets,
    float* __restrict__ mined, double* __restrict__ acc, int* __restrict__ num_pos) {
  __shared__ float ldsA[LDS_FLOATS];
  __shared__ float ldsB[LDS_FLOATS];

  const int tid = (int)threadIdx.x;
  const int wid = tid >> 6, lane = tid & 63;
  const int row = tid >> 2, part = tid & 3;
  const int t0 = (int)blockIdx.x * TILES_PER_BLOCK;
  const char* cbase = (const char*)conf_data;

  float loc_v = 0.f, ce_pos = 0.f;

  stage_tile(cbase, (uint32_t)t0, ldsA, wid, lane);
  int tgtA = conf_targets[(size_t)t0 * TILE_ROWS + row];
  int tgtB = 0;
  DRAIN_BARRIER();

#pragma unroll
  for (int u = 0; u < 3; ++u) {
    const int tA = t0 + 2 * u;

    stage_tile(cbase, (uint32_t)(tA + 1), ldsB, wid, lane);
    tgtB = conf_targets[(size_t)(tA + 1) * TILE_ROWS + row];
    compute_tile(ldsA, tA, tgtA, row, part, loc_data, loc_targets,
                 mined, num_pos, loc_v, ce_pos);
    DRAIN_BARRIER();

    if (u < 2) {
      stage_tile(cbase, (uint32_t)(tA + 2), ldsA, wid, lane);
      tgtA = conf_targets[(size_t)(tA + 2) * TILE_ROWS + row];
    }
    compute_tile(ldsB, tA + 1, tgtB, row, part, loc_data, loc_targets,
                 mined, num_pos, loc_v, ce_pos);
    if (u < 2) DRAIN_BARRIER();
  }

  __shared__ float red[2][4];
  float r0 = wave_reduce_sum(loc_v);
  float r1 = wave_reduce_sum(ce_pos);
  if (lane == 0) { red[0][wid] = r0; red[1][wid] = r1; }
  __syncthreads();
  if (tid == 0) {
    float s0 = 0.f, s1 = 0.f;
#pragma unroll
    for (int i = 0; i < 4; ++i) { s0 += red[0][i]; s1 += red[1][i]; }
    if (s0 != 0.f) atomicAdd(&acc[0], (double)s0);
    if (s1 != 0.f) atomicAdd(&acc[1], (double)s1);
  }
}

__global__ __launch_bounds__(1024) void mb_select(
    const float* __restrict__ mined, const int* __restrict__ num_pos,
    double* __restrict__ acc) {
  const int b = blockIdx.x;
  const float* __restrict__ row = mined + (size_t)b * NP;
  const int tid = threadIdx.x;
  const int wid = tid >> 6;
  const int lane = tid & 63;

  __shared__ int hist[16][256];
  __shared__ int total[256];
  __shared__ int suffix[256];
  __shared__ unsigned s_prefix;
  __shared__ int s_k;

  if (tid == 0) {
    int k = NEG_POS * num_pos[b];
    if (k > NP - 1) k = NP - 1;
    s_k = k;
    s_prefix = 0u;
  }
  __syncthreads();

  for (int shift = 24; shift >= 0; shift -= 8) {
    for (int i = tid; i < 16 * 256; i += 1024) ((int*)hist)[i] = 0;
    __syncthreads();
    const unsigned mask = (shift == 24) ? 0u : (0xFFFFFFFFu << (shift + 8));
    const unsigned pfx = s_prefix;
    const int kcur = s_k;

    for (int q = tid; q < NP / 4; q += 1024) {
      const float4 v = reinterpret_cast<const float4*>(row)[q];
      unsigned u;
      u = __float_as_uint(v.x); if ((u & mask) == pfx) atomicAdd(&hist[wid][(u >> shift) & 255], 1);
      u = __float_as_uint(v.y); if ((u & mask) == pfx) atomicAdd(&hist[wid][(u >> shift) & 255], 1);
      u = __float_as_uint(v.z); if ((u & mask) == pfx) atomicAdd(&hist[wid][(u >> shift) & 255], 1);
      u = __float_as_uint(v.w); if ((u & mask) == pfx) atomicAdd(&hist[wid][(u >> shift) & 255], 1);
    }
    __syncthreads();

    if (tid < 256) {
      int t = 0;
#pragma unroll
      for (int w = 0; w < 16; ++w) t += hist[w][tid];
      total[tid] = t;
    }
    __syncthreads();

    if (wid == 0) {
      const int t0_ = total[4 * lane + 0];
      const int t1_ = total[4 * lane + 1];
      const int t2_ = total[4 * lane + 2];
      const int t3_ = total[4 * lane + 3];
      const int s3 = t3_;
      const int s2 = t2_ + s3;
      const int s1 = t1_ + s2;
      const int s0 = t0_ + s1;
      int acc_ = s0;
#pragma unroll
      for (int off = 1; off < 64; off <<= 1) {
        const int o = __shfl_down(acc_, off, 64);
        if (lane + off < 64) acc_ += o;
      }
      const int excl = acc_ - s0;
      suffix[4 * lane + 0] = s0 + excl;
      suffix[4 * lane + 1] = s1 + excl;
      suffix[4 * lane + 2] = s2 + excl;
      suffix[4 * lane + 3] = s3 + excl;
    }
    __syncthreads();

    if (tid < 256) {
      const int cs = suffix[tid] - total[tid];
      if (kcur >= cs && kcur < cs + total[tid]) {
        s_prefix = pfx | ((unsigned)tid << shift);
        s_k = kcur - cs;
      }
    }
    __syncthreads();
  }

  const unsigned vbits = s_prefix;
  float sum = 0.f;
  for (int q = tid; q < NP / 4; q += 1024) {
    const float4 v = reinterpret_cast<const float4*>(row)[q];
    if (__float_as_uint(v.x) > vbits) sum += v.x;
    if (__float_as_uint(v.y) > vbits) sum += v.y;
    if (__float_as_uint(v.z) > vbits) sum += v.z;
    if (__float_as_uint(v.w) > vbits) sum += v.w;
  }

  __shared__ float wsum[16];
  float w = wave_reduce_sum(sum);
  if (lane == 0) wsum[wid] = w;
  __syncthreads();
  if (tid == 0) {
    float t = 0.f;
#pragma unroll
    for (int i = 0; i < 16; ++i) t += wsum[i];
    atomicAdd(&acc[2], (double)t);
  }
}

__global__ void mb_finalize(const double* __restrict__ acc,
                            const int* __restrict__ num_pos,
                            float* __restrict__ out) {
  if (threadIdx.x == 0) {
    int tot = 0;
#pragma unroll
    for (int i = 0; i < NB; ++i) tot += num_pos[i];
    const double n = (double)(tot > 0 ? tot : 1);
    out[0] = (float)((acc[0] + acc[1] + acc[2]) / n);
  }
}

extern "C" void kernel_launch(void* const* d_in, const int* in_sizes, int n_in,
                              void* d_out, int out_size, void* d_ws, size_t ws_size,
                              hipStream_t stream) {
  const float* loc_data     = (const float*)d_in[0];
  const float* conf_data    = (const float*)d_in[1];
  const float* loc_targets  = (const float*)d_in[2];
  const int*   conf_targets = (const int*)d_in[3];
  float* out = (float*)d_out;

  float*  mined   = (float*)d_ws;
  double* acc     = (double*)((char*)d_ws + MINED_BYTES);
  int*    num_pos = (int*)((char*)d_ws + MINED_BYTES + 3 * sizeof(double));

  // diagnostics (outputs overwritten by mb_main)
  probe_stream<<<PROBE_BLOCKS, 256, 0, stream>>>(
      (const float4*)conf_data, mined);
  probe_exp<<<PROBE_BLOCKS, 256, 0, stream>>>(
      (const float4*)conf_data, mined);

  mb_init<<<1, 64, 0, stream>>>(acc, num_pos);

  mb_main<<<MAIN_BLOCKS, 256, 0, stream>>>(loc_data, conf_data, loc_targets,
                                           conf_targets, mined, acc, num_pos);

  mb_select<<<NB, 1024, 0, stream>>>(mined, num_pos, acc);

  mb_finalize<<<1, 64, 0, stream>>>(acc, num_pos, out);
}

// Round 13
// 214.798 us; speedup vs baseline: 1.2398x; 1.2398x over previous
//
#include <hip/hip_runtime.h>
#include <cmath>
#include <cstdint>

#define NB 32
#define NP 24564
#define NC 81
#define NEG_POS 3

static constexpr size_t MINED_ELEMS = (size_t)NB * NP;             // 786,048
static constexpr size_t MINED_BYTES = MINED_ELEMS * sizeof(float); // 3,144,192

#define NTILES4 ((int)(MINED_ELEMS / 4))   // 196,512 4-row tiles (NP%4==0: no tile straddles a batch row)
#define MAIN_BLOCKS 2048                   // 8 blocks/CU -> 32 waves/CU (probe TLP)
#define TOTAL_WAVES (MAIN_BLOCKS * 4)      // 8192

// ws layout:
//   [0, MINED_BYTES)                    float mined[NB*NP]
//   [MINED_BYTES, +24)                  double acc[3]  {loc_loss, ce_pos_sum, neg_sum}
//   [MINED_BYTES+24, +24+4*NB)          int   num_pos[NB]

__device__ __forceinline__ float wave_reduce_sum(float v) {
#pragma unroll
  for (int off = 32; off > 0; off >>= 1) v += __shfl_down(v, off, 64);
  return v;
}

__device__ __forceinline__ float smooth_l1_4(float4 a, float4 t) {
  float acc = 0.f, d, ax;
  d = a.x - t.x; ax = fabsf(d); acc += (ax < 1.f) ? 0.5f * d * d : ax - 0.5f;
  d = a.y - t.y; ax = fabsf(d); acc += (ax < 1.f) ? 0.5f * d * d : ax - 0.5f;
  d = a.z - t.z; ax = fabsf(d); acc += (ax < 1.f) ? 0.5f * d * d : ax - 0.5f;
  d = a.w - t.w; ax = fabsf(d); acc += (ax < 1.f) ? 0.5f * d * d : ax - 0.5f;
  return acc;
}

__global__ void mb_init(double* __restrict__ acc, int* __restrict__ num_pos) {
  int t = threadIdx.x;
  if (t < 3) acc[t] = 0.0;
  if (t < NB) num_pos[t] = 0;
}

// Probe-shaped CE kernel: grid-stride over 4-row tiles (81 float4 each).
// Per wave per iteration: 2 coalesced float4 loads (prefetched one tile
// ahead) -> wave-private LDS slice (no barriers; DS ops in-order per wave)
// -> 16 lanes per row reduce from LDS. 32 waves/CU do the latency hiding.
__global__ __launch_bounds__(256, 8) void mb_main(
    const float* __restrict__ loc_data, const float* __restrict__ conf_data,
    const float* __restrict__ loc_targets, const int* __restrict__ conf_targets,
    float* __restrict__ mined, double* __restrict__ acc, int* __restrict__ num_pos) {
  __shared__ float lds[4][324];   // 1296 B per wave slice (16B-aligned)
  __shared__ float red[2][4];

  const int tid  = (int)threadIdx.x;
  const int wid  = tid >> 6, lane = tid & 63;
  const int r    = lane >> 4, il = lane & 15;
  float* __restrict__ L = lds[wid];

  float loc_v = 0.f, ce_pos = 0.f;

  int tile = (int)blockIdx.x * 4 + wid;   // consecutive waves -> consecutive tiles
  float4 c0, c1;
  {
    const float4* __restrict__ src =
        reinterpret_cast<const float4*>(conf_data) + (size_t)tile * 81;
    c0 = src[lane];
    if (lane < 17) c1 = src[64 + lane];
  }

  while (tile < NTILES4) {
    const int nt = tile + TOTAL_WAVES;

    // stage current tile into the wave-private slice (compiler emits the
    // precise vmcnt for c0/c1; newer prefetch loads stay outstanding)
    *reinterpret_cast<float4*>(&L[4 * lane]) = c0;
    if (lane < 17) *reinterpret_cast<float4*>(&L[256 + 4 * lane]) = c1;

    // prefetch next tile: in flight across all of this tile's compute
    if (nt < NTILES4) {
      const float4* __restrict__ src =
          reinterpret_cast<const float4*>(conf_data) + (size_t)nt * 81;
      c0 = src[lane];
      if (lane < 17) c1 = src[64 + lane];
    }
    __builtin_amdgcn_sched_barrier(0);   // keep prefetch above the compute

    // wave-uniform targets for the 4 rows of this tile
    const int4 tg = *reinterpret_cast<const int4*>(conf_targets + (size_t)tile * 4);
    const int tgt = (r == 0) ? tg.x : (r == 1) ? tg.y : (r == 2) ? tg.z : tg.w;

    const int rb = 81 * r;
    float e = __expf(L[rb + il]) + __expf(L[rb + il + 16]) +
              __expf(L[rb + il + 32]) + __expf(L[rb + il + 48]) +
              __expf(L[rb + il + 64]);
    if (il == 0) e += __expf(L[rb + 80]);
    e += __shfl_xor(e, 1, 64);
    e += __shfl_xor(e, 2, 64);
    e += __shfl_xor(e, 4, 64);
    e += __shfl_xor(e, 8, 64);

    if (il == 0) {
      const float tv = L[rb + tgt];
      const float ce = __logf(e) - tv;   // unstabilized LSE safe: |x| < ~6
      const int flat = tile * 4 + r;
      const int is_pos = tgt > 0;
      mined[flat] = is_pos ? 0.f : ce;   // ce > 0 always; bits order as floats
      if (is_pos) {
        ce_pos += ce;
        loc_v += smooth_l1_4(
            *reinterpret_cast<const float4*>(loc_data + (size_t)flat * 4),
            *reinterpret_cast<const float4*>(loc_targets + (size_t)flat * 4));
        atomicAdd(&num_pos[flat / NP], 1);   // rare (~2% of rows)
      }
    }
    tile = nt;
  }

  // block reduction for the two global sums (single barrier, end of kernel)
  float r0 = wave_reduce_sum(loc_v);
  float r1 = wave_reduce_sum(ce_pos);
  if (lane == 0) { red[0][wid] = r0; red[1][wid] = r1; }
  __syncthreads();
  if (tid == 0) {
    float s0 = 0.f, s1 = 0.f;
#pragma unroll
    for (int i = 0; i < 4; ++i) { s0 += red[0][i]; s1 += red[1][i]; }
    if (s0 != 0.f) atomicAdd(&acc[0], (double)s0);
    if (s1 != 0.f) atomicAdd(&acc[1], (double)s1);
  }
}

// One block per batch row: radix-select the (k+1)-th largest of mined[b,:]
// (k = min(3*num_pos, NP-1)), then sum elements strictly greater.
__global__ __launch_bounds__(1024) void mb_select(
    const float* __restrict__ mined, const int* __restrict__ num_pos,
    double* __restrict__ acc) {
  const int b = blockIdx.x;
  const float* __restrict__ row = mined + (size_t)b * NP;
  const int tid = threadIdx.x;
  const int wid = tid >> 6;
  const int lane = tid & 63;

  __shared__ int hist[16][256];
  __shared__ int total[256];
  __shared__ int suffix[256];
  __shared__ unsigned s_prefix;
  __shared__ int s_k;

  if (tid == 0) {
    int k = NEG_POS * num_pos[b];
    if (k > NP - 1) k = NP - 1;
    s_k = k;
    s_prefix = 0u;
  }
  __syncthreads();

  for (int shift = 24; shift >= 0; shift -= 8) {
    for (int i = tid; i < 16 * 256; i += 1024) ((int*)hist)[i] = 0;
    __syncthreads();
    const unsigned mask = (shift == 24) ? 0u : (0xFFFFFFFFu << (shift + 8));
    const unsigned pfx = s_prefix;
    const int kcur = s_k;

    for (int q = tid; q < NP / 4; q += 1024) {
      const float4 v = reinterpret_cast<const float4*>(row)[q];
      unsigned u;
      u = __float_as_uint(v.x); if ((u & mask) == pfx) atomicAdd(&hist[wid][(u >> shift) & 255], 1);
      u = __float_as_uint(v.y); if ((u & mask) == pfx) atomicAdd(&hist[wid][(u >> shift) & 255], 1);
      u = __float_as_uint(v.z); if ((u & mask) == pfx) atomicAdd(&hist[wid][(u >> shift) & 255], 1);
      u = __float_as_uint(v.w); if ((u & mask) == pfx) atomicAdd(&hist[wid][(u >> shift) & 255], 1);
    }
    __syncthreads();

    if (tid < 256) {
      int t = 0;
#pragma unroll
      for (int w = 0; w < 16; ++w) t += hist[w][tid];
      total[tid] = t;
    }
    __syncthreads();

    if (wid == 0) {
      const int t0_ = total[4 * lane + 0];
      const int t1_ = total[4 * lane + 1];
      const int t2_ = total[4 * lane + 2];
      const int t3_ = total[4 * lane + 3];
      const int s3 = t3_;
      const int s2 = t2_ + s3;
      const int s1 = t1_ + s2;
      const int s0 = t0_ + s1;
      int acc_ = s0;
#pragma unroll
      for (int off = 1; off < 64; off <<= 1) {
        const int o = __shfl_down(acc_, off, 64);
        if (lane + off < 64) acc_ += o;
      }
      const int excl = acc_ - s0;
      suffix[4 * lane + 0] = s0 + excl;
      suffix[4 * lane + 1] = s1 + excl;
      suffix[4 * lane + 2] = s2 + excl;
      suffix[4 * lane + 3] = s3 + excl;
    }
    __syncthreads();

    if (tid < 256) {
      const int cs = suffix[tid] - total[tid];
      if (kcur >= cs && kcur < cs + total[tid]) {
        s_prefix = pfx | ((unsigned)tid << shift);
        s_k = kcur - cs;
      }
    }
    __syncthreads();
  }

  const unsigned vbits = s_prefix;
  float sum = 0.f;
  for (int q = tid; q < NP / 4; q += 1024) {
    const float4 v = reinterpret_cast<const float4*>(row)[q];
    if (__float_as_uint(v.x) > vbits) sum += v.x;
    if (__float_as_uint(v.y) > vbits) sum += v.y;
    if (__float_as_uint(v.z) > vbits) sum += v.z;
    if (__float_as_uint(v.w) > vbits) sum += v.w;
  }

  __shared__ float wsum[16];
  float w = wave_reduce_sum(sum);
  if (lane == 0) wsum[wid] = w;
  __syncthreads();
  if (tid == 0) {
    float t = 0.f;
#pragma unroll
    for (int i = 0; i < 16; ++i) t += wsum[i];
    atomicAdd(&acc[2], (double)t);
  }
}

__global__ void mb_finalize(const double* __restrict__ acc,
                            const int* __restrict__ num_pos,
                            float* __restrict__ out) {
  if (threadIdx.x == 0) {
    int tot = 0;
#pragma unroll
    for (int i = 0; i < NB; ++i) tot += num_pos[i];
    const double n = (double)(tot > 0 ? tot : 1);
    out[0] = (float)((acc[0] + acc[1] + acc[2]) / n);
  }
}

extern "C" void kernel_launch(void* const* d_in, const int* in_sizes, int n_in,
                              void* d_out, int out_size, void* d_ws, size_t ws_size,
                              hipStream_t stream) {
  const float* loc_data     = (const float*)d_in[0];
  const float* conf_data    = (const float*)d_in[1];
  const float* loc_targets  = (const float*)d_in[2];
  const int*   conf_targets = (const int*)d_in[3];
  float* out = (float*)d_out;

  float*  mined   = (float*)d_ws;
  double* acc     = (double*)((char*)d_ws + MINED_BYTES);
  int*    num_pos = (int*)((char*)d_ws + MINED_BYTES + 3 * sizeof(double));

  mb_init<<<1, 64, 0, stream>>>(acc, num_pos);

  mb_main<<<MAIN_BLOCKS, 256, 0, stream>>>(loc_data, conf_data, loc_targets,
                                           conf_targets, mined, acc, num_pos);

  mb_select<<<NB, 1024, 0, stream>>>(mined, num_pos, acc);

  mb_finalize<<<1, 64, 0, stream>>>(acc, num_pos, out);
}

// Round 14
// 103.649 us; speedup vs baseline: 2.5692x; 2.0724x over previous
//
#include <hip/hip_runtime.h>
#include <cmath>
#include <cstdint>

#define NB 32
#define NP 24564
#define NC 81
#define NEG_POS 3

static constexpr size_t MINED_ELEMS = (size_t)NB * NP;             // 786,048
static constexpr size_t MINED_BYTES = MINED_ELEMS * sizeof(float); // 3,144,192

#define NTILES4 ((int)(MINED_ELEMS / 4))   // 196,512 = 8188 * 24 exactly
#define MAIN_BLOCKS 2047                   // 4 waves each -> 8188 waves
#define TOTAL_WAVES (MAIN_BLOCKS * 4)
#define ITERS 24

// ws layout:
//   [0, MINED_BYTES)                    float mined[NB*NP]  (sign bit = positive row, |v| = ce)
//   [MINED_BYTES, +24)                  double acc[3]  {loc_loss, ce_pos_sum, neg_sum}
//   [MINED_BYTES+24, +24+4*NB)          int   num_pos[NB]

__device__ __forceinline__ float wave_reduce_sum(float v) {
#pragma unroll
  for (int off = 32; off > 0; off >>= 1) v += __shfl_down(v, off, 64);
  return v;
}

__device__ __forceinline__ float smooth_l1_4(float4 a, float4 t) {
  float acc = 0.f, d, ax;
  d = a.x - t.x; ax = fabsf(d); acc += (ax < 1.f) ? 0.5f * d * d : ax - 0.5f;
  d = a.y - t.y; ax = fabsf(d); acc += (ax < 1.f) ? 0.5f * d * d : ax - 0.5f;
  d = a.z - t.z; ax = fabsf(d); acc += (ax < 1.f) ? 0.5f * d * d : ax - 0.5f;
  d = a.w - t.w; ax = fabsf(d); acc += (ax < 1.f) ? 0.5f * d * d : ax - 0.5f;
  return acc;
}

__global__ void mb_init(double* __restrict__ acc, int* __restrict__ num_pos) {
  int t = threadIdx.x;
  if (t < 3) acc[t] = 0.0;
  if (t < NB) num_pos[t] = 0;
}

// Branch-free CE kernel. Per wave per iteration: 2 unconditional coalesced
// float4 loads (depth-1 prefetch) -> wave-private LDS slice -> 16 lanes/row
// reduce -> ONE unconditional mined store (16-lane redundant per row).
// No conditional VMEM anywhere -> compiler emits precise rolling vmcnt(N)
// waits; the store ack never blocks (vmcnt retires in order).
__global__ __launch_bounds__(256, 8) void mb_main(
    const float* __restrict__ conf_data, const int* __restrict__ conf_targets,
    float* __restrict__ mined) {
  __shared__ float lds[4][332];   // 324 data + dump slot (16B aligned-ish)

  const int tid  = (int)threadIdx.x;
  const int wid  = tid >> 6, lane = tid & 63;
  const int r    = lane >> 4, il = lane & 15;
  float* __restrict__ L = lds[wid];

  const int l17   = (lane < 17) ? lane : 16;          // clamped src index
  const int ldst1 = (lane < 17) ? (256 + 4 * l17) : 328;  // dump for lanes>=17

  int tile = (int)blockIdx.x * 4 + wid;
  float4 c0, c1;
  {
    const float4* __restrict__ src =
        reinterpret_cast<const float4*>(conf_data) + (size_t)tile * 81;
    c0 = src[lane];
    c1 = src[64 + l17];
  }

#pragma unroll 1
  for (int k = 0; k < ITERS; ++k) {
    // stage current tile (waits only on c0/c1's loads: precise vmcnt)
    *reinterpret_cast<float4*>(&L[4 * lane]) = c0;
    *reinterpret_cast<float4*>(&L[ldst1]) = c1;

    // prefetch next tile unconditionally (clamped index on last iter)
    {
      int nt = tile + TOTAL_WAVES;
      nt = (nt < NTILES4) ? nt : tile;
      const float4* __restrict__ src =
          reinterpret_cast<const float4*>(conf_data) + (size_t)nt * 81;
      c0 = src[lane];
      c1 = src[64 + l17];
    }
    __builtin_amdgcn_sched_barrier(0);   // keep prefetch above compute

    // wave-uniform targets for the 4 rows
    const int4 tg = *reinterpret_cast<const int4*>(conf_targets + (size_t)tile * 4);
    const int tgt = (r == 0) ? tg.x : (r == 1) ? tg.y : (r == 2) ? tg.z : tg.w;

    const int rb = 81 * r;
    float e = __expf(L[rb + il]) + __expf(L[rb + il + 16]) +
              __expf(L[rb + il + 32]) + __expf(L[rb + il + 48]) +
              __expf(L[rb + il + 64]);
    if (il == 0) e += __expf(L[rb + 80]);   // VALU-only divergence: harmless
    e += __shfl_xor(e, 1, 64);
    e += __shfl_xor(e, 2, 64);
    e += __shfl_xor(e, 4, 64);
    e += __shfl_xor(e, 8, 64);

    const float tv = L[rb + tgt];           // 16-lane broadcast gather
    const float ce = __logf(e) - tv;        // unstabilized LSE safe: |x| < ~6
    const float val = (tgt > 0) ? -ce : ce; // sign bit marks positive rows
    mined[tile * 4 + r] = val;              // unconditional, 16-lane redundant

    tile += TOTAL_WAVES;
  }
}

// One block per batch row. Pre-pass: positives (sign bit) -> num_pos, ce_pos,
// loc smooth-L1; then radix-select (sign-set values masked to 0.0 = exact old
// semantics) and strict-greater negative sum.
__global__ __launch_bounds__(1024) void mb_select(
    const float* __restrict__ mined, const float* __restrict__ loc_data,
    const float* __restrict__ loc_targets, double* __restrict__ acc,
    int* __restrict__ num_pos) {
  const int b = blockIdx.x;
  const float* __restrict__ row = mined + (size_t)b * NP;
  const int tid = threadIdx.x;
  const int wid = tid >> 6;
  const int lane = tid & 63;

  __shared__ int hist[16][256];
  __shared__ int total[256];
  __shared__ int suffix[256];
  __shared__ unsigned s_prefix;
  __shared__ int s_k;
  __shared__ int s_np;

  // ---- pre-pass: positives ----
  {
    int np = 0;
    float cp = 0.f, lv = 0.f;
    for (int q = tid; q < NP / 4; q += 1024) {
      const float4 v = reinterpret_cast<const float4*>(row)[q];
      const float vv[4] = {v.x, v.y, v.z, v.w};
#pragma unroll
      for (int j = 0; j < 4; ++j) {
        if (__float_as_uint(vv[j]) >> 31) {
          np++;
          cp += -vv[j];
          const size_t flat = (size_t)b * NP + 4 * q + j;
          lv += smooth_l1_4(
              *reinterpret_cast<const float4*>(loc_data + flat * 4),
              *reinterpret_cast<const float4*>(loc_targets + flat * 4));
        }
      }
    }
    __shared__ float rednp[16], redcp[16], redlv[16];
    float wnp = wave_reduce_sum((float)np);
    float wcp = wave_reduce_sum(cp);
    float wlv = wave_reduce_sum(lv);
    if (lane == 0) { rednp[wid] = wnp; redcp[wid] = wcp; redlv[wid] = wlv; }
    __syncthreads();
    if (tid == 0) {
      float tnp = 0.f, tcp = 0.f, tlv = 0.f;
#pragma unroll
      for (int i = 0; i < 16; ++i) { tnp += rednp[i]; tcp += redcp[i]; tlv += redlv[i]; }
      const int npi = (int)tnp;
      s_np = npi;
      num_pos[b] = npi;
      if (tcp != 0.f) atomicAdd(&acc[1], (double)tcp);
      if (tlv != 0.f) atomicAdd(&acc[0], (double)tlv);
      int k = NEG_POS * npi;
      if (k > NP - 1) k = NP - 1;
      s_k = k;
      s_prefix = 0u;
    }
    __syncthreads();
  }

  // ---- radix select over masked values (sign-set -> 0.0) ----
  for (int shift = 24; shift >= 0; shift -= 8) {
    for (int i = tid; i < 16 * 256; i += 1024) ((int*)hist)[i] = 0;
    __syncthreads();
    const unsigned mask = (shift == 24) ? 0u : (0xFFFFFFFFu << (shift + 8));
    const unsigned pfx = s_prefix;
    const int kcur = s_k;

    for (int q = tid; q < NP / 4; q += 1024) {
      const float4 v = reinterpret_cast<const float4*>(row)[q];
      unsigned u;
      u = __float_as_uint(v.x); u = (u >> 31) ? 0u : u; if ((u & mask) == pfx) atomicAdd(&hist[wid][(u >> shift) & 255], 1);
      u = __float_as_uint(v.y); u = (u >> 31) ? 0u : u; if ((u & mask) == pfx) atomicAdd(&hist[wid][(u >> shift) & 255], 1);
      u = __float_as_uint(v.z); u = (u >> 31) ? 0u : u; if ((u & mask) == pfx) atomicAdd(&hist[wid][(u >> shift) & 255], 1);
      u = __float_as_uint(v.w); u = (u >> 31) ? 0u : u; if ((u & mask) == pfx) atomicAdd(&hist[wid][(u >> shift) & 255], 1);
    }
    __syncthreads();

    if (tid < 256) {
      int t = 0;
#pragma unroll
      for (int w = 0; w < 16; ++w) t += hist[w][tid];
      total[tid] = t;
    }
    __syncthreads();

    if (wid == 0) {
      const int t0_ = total[4 * lane + 0];
      const int t1_ = total[4 * lane + 1];
      const int t2_ = total[4 * lane + 2];
      const int t3_ = total[4 * lane + 3];
      const int s3 = t3_;
      const int s2 = t2_ + s3;
      const int s1 = t1_ + s2;
      const int s0 = t0_ + s1;
      int acc_ = s0;
#pragma unroll
      for (int off = 1; off < 64; off <<= 1) {
        const int o = __shfl_down(acc_, off, 64);
        if (lane + off < 64) acc_ += o;
      }
      const int excl = acc_ - s0;
      suffix[4 * lane + 0] = s0 + excl;
      suffix[4 * lane + 1] = s1 + excl;
      suffix[4 * lane + 2] = s2 + excl;
      suffix[4 * lane + 3] = s3 + excl;
    }
    __syncthreads();

    if (tid < 256) {
      const int cs = suffix[tid] - total[tid];
      if (kcur >= cs && kcur < cs + total[tid]) {
        s_prefix = pfx | ((unsigned)tid << shift);
        s_k = kcur - cs;
      }
    }
    __syncthreads();
  }

  const unsigned vbits = s_prefix;   // pivot bit pattern (masked domain)
  float sum = 0.f;
  for (int q = tid; q < NP / 4; q += 1024) {
    const float4 v = reinterpret_cast<const float4*>(row)[q];
    unsigned u;
    u = __float_as_uint(v.x); u = (u >> 31) ? 0u : u; if (u > vbits) sum += v.x;
    u = __float_as_uint(v.y); u = (u >> 31) ? 0u : u; if (u > vbits) sum += v.y;
    u = __float_as_uint(v.z); u = (u >> 31) ? 0u : u; if (u > vbits) sum += v.z;
    u = __float_as_uint(v.w); u = (u >> 31) ? 0u : u; if (u > vbits) sum += v.w;
  }

  __shared__ float wsum[16];
  float w = wave_reduce_sum(sum);
  if (lane == 0) wsum[wid] = w;
  __syncthreads();
  if (tid == 0) {
    float t = 0.f;
#pragma unroll
    for (int i = 0; i < 16; ++i) t += wsum[i];
    atomicAdd(&acc[2], (double)t);
  }
}

__global__ void mb_finalize(const double* __restrict__ acc,
                            const int* __restrict__ num_pos,
                            float* __restrict__ out) {
  if (threadIdx.x == 0) {
    int tot = 0;
#pragma unroll
    for (int i = 0; i < NB; ++i) tot += num_pos[i];
    const double n = (double)(tot > 0 ? tot : 1);
    out[0] = (float)((acc[0] + acc[1] + acc[2]) / n);
  }
}

extern "C" void kernel_launch(void* const* d_in, const int* in_sizes, int n_in,
                              void* d_out, int out_size, void* d_ws, size_t ws_size,
                              hipStream_t stream) {
  const float* loc_data     = (const float*)d_in[0];
  const float* conf_data    = (const float*)d_in[1];
  const float* loc_targets  = (const float*)d_in[2];
  const int*   conf_targets = (const int*)d_in[3];
  float* out = (float*)d_out;

  float*  mined   = (float*)d_ws;
  double* acc     = (double*)((char*)d_ws + MINED_BYTES);
  int*    num_pos = (int*)((char*)d_ws + MINED_BYTES + 3 * sizeof(double));

  mb_init<<<1, 64, 0, stream>>>(acc, num_pos);

  mb_main<<<MAIN_BLOCKS, 256, 0, stream>>>(conf_data, conf_targets, mined);

  mb_select<<<NB, 1024, 0, stream>>>(mined, loc_data, loc_targets, acc, num_pos);

  mb_finalize<<<1, 64, 0, stream>>>(acc, num_pos, out);
}